// Round 4
// baseline (4971.905 us; speedup 1.0000x reference)
//
#include <hip/hip_runtime.h>

// B=128, S=1024, F_IN=128, H=256, BB=256, F_OUT=128
#define Bn   128
#define Sn   1024
#define FIN  128
#define Hn   256
#define FOUT 128
#define KBB  384
#define NT1  1024   // phase-1 threads (16 waves)

// H-loop chunk partition (32 chunks of 16B per thread):
//   c in [0,NV)        -> VGPR-resident (loaded once, asm-pinned)  NV*4 VGPRs
//   c in [NV,NV+NL)    -> LDS-resident (loaded once)               NL*16KB dyn smem
//   c in [NV+NL,32)    -> streamed from L2 every step (unroll 2)
// Round-3 lesson: NV=12 pinned + unroll-4 streams peaked >128 regs -> allocator
// spilled ALL pinned regs to scratch (VGPR_Count=60, scratch reload 192KB/step).
// NV=8 + unroll-2 streams targets ~100 regs peak, under the 128 hard cap.
#define NV 8
#define NL 9
#define DYN_SMEM (NL * 1024 * 8 * 2)   // 147456 bytes (+11.8KB static = 159KB < 160KB)

// packed weight layout in d_ws (halves):
//   Wb_p [48][256][8]  -> 98304   (layers 0-15 = x-part, 16-47 = h-part)
//   W4_p [32][1024][8] -> 262144  (N = [ff1|ff2|ta|tb])
//   Wo_p [32][128][8]  -> 32768
//   hbuf [B*S*H]  fp16 -> 33554432 (split-Y path)
//   xc   [B*S*BB] fp16 -> 33554432 (precomputed x @ Wb_x)
#define WB_OFF 0
#define W4_OFF 98304
#define WO_OFF 360448
#define WS_HALVES 393216
#define HBUF_OFF WS_HALVES
#define XC_OFF (HBUF_OFF + (size_t)Bn * Sn * Hn)
#define WS_SPLIT_BYTES ((size_t)(WS_HALVES + (size_t)Bn * Sn * Hn) * 2)
#define WS_FULL_BYTES ((XC_OFF + (size_t)Bn * Sn * Hn) * 2)

typedef _Float16 h2 __attribute__((ext_vector_type(2)));
typedef _Float16 h8 __attribute__((ext_vector_type(8)));

__device__ __forceinline__ float dot2f(h2 a, h2 b, float c) {
#if __has_builtin(__builtin_amdgcn_fdot2)
  return __builtin_amdgcn_fdot2(a, b, c, false);   // v_dot2_f32_f16
#else
  return c + (float)a[0] * (float)b[0] + (float)a[1] * (float)b[1];
#endif
}
__device__ __forceinline__ void dot8_4(h8 v, h8 w, float& c0, float& c1, float& c2, float& c3) {
  h2 v0 = {v[0], v[1]}, v1 = {v[2], v[3]}, v2 = {v[4], v[5]}, v3 = {v[6], v[7]};
  h2 w0 = {w[0], w[1]}, w1 = {w[2], w[3]}, w2 = {w[4], w[5]}, w3 = {w[6], w[7]};
  c0 = dot2f(v0, w0, c0); c1 = dot2f(v1, w1, c1);
  c2 = dot2f(v2, w2, c2); c3 = dot2f(v3, w3, c3);
}

// fp32 -> fp16 packing (verified layout)
__global__ __launch_bounds__(256) void pack_w(
    const float* __restrict__ Wb, const float* __restrict__ W1,
    const float* __restrict__ W2, const float* __restrict__ W3,
    const float* __restrict__ W4, const float* __restrict__ Wo,
    _Float16* __restrict__ ws) {
  int p = blockIdx.x * 256 + threadIdx.x;
  if (p >= WS_HALVES) return;
  float v;
  if (p < W4_OFF) {                       // backbone [384,256] row-major
    int r = p & 7, j = (p >> 3) & 255;
    int k = ((p >> 11) << 3) | r;
    v = Wb[k * 256 + j];
  } else if (p < WO_OFF) {                // heads concat: N = [ff1|ff2|ta|tb]
    int q = p - W4_OFF;
    int r = q & 7, j = (q >> 3) & 1023;
    int k = ((q >> 13) << 3) | r;
    int jj = j & 255;
    const float* Ws = (j < 256) ? W1 : (j < 512) ? W2 : (j < 768) ? W3 : W4;
    v = Ws[k * 256 + jj];
  } else {                                // Wout [256,128]
    int q = p - WO_OFF;
    int r = q & 7, j = (q >> 3) & 127;
    int k = ((q >> 10) << 3) | r;
    v = Wo[k * 128 + j];
  }
  ws[p] = (_Float16)v;
}

// xc[r,j] = sum_k x[r,k] * Wb[k,j]  (k<128, the non-recurrent x-part of Z).
// 2048 WGs x 256 threads; WG computes 64 rows x 256 cols. Weight column per
// thread lives in 16 h8 regs; x rows staged fp16 in LDS (broadcast reads).
__global__ __launch_bounds__(256) void xgemm(
    const float* __restrict__ x, const _Float16* __restrict__ ws,
    _Float16* __restrict__ xc) {
  __shared__ __align__(16) _Float16 sX[64 * 128];   // 16 KB
  const int tid = threadIdx.x;
  const size_t r0 = (size_t)blockIdx.x * 64;
  const float* xb = x + r0 * 128;
#pragma unroll
  for (int m = 0; m < 32; ++m)
    sX[m * 256 + tid] = (_Float16)xb[m * 256 + tid];
  const _Float16* gX = ws + WB_OFF + (size_t)tid * 8;   // layers 0-15 = x-part
  h8 wx[16];
#pragma unroll
  for (int L = 0; L < 16; ++L) wx[L] = *(const h8*)(gX + (size_t)L * 2048);
  __syncthreads();
  for (int r = 0; r < 64; ++r) {
    float c0 = 0.f, c1 = 0.f, c2 = 0.f, c3 = 0.f;
#pragma unroll
    for (int L = 0; L < 16; ++L) {
      h8 v = *(const h8*)&sX[r * 128 + L * 8];          // broadcast
      dot8_4(v, wx[L], c0, c1, c2, c3);
    }
    xc[(r0 + r) * 256 + tid] = (_Float16)(c0 + c1 + c2 + c3);
  }
}

// Phase 1: one 1024-thread WG per batch element. Measured (3 rounds): the
// per-CU L2 port sustains ~55 B/cy; step time == streamed_weight_bytes / 55.
// Residency: NV=8 H-chunks pinned in VGPRs + NL=9 H-chunks in LDS (144KB).
// XC=1: x-part of Z precomputed (xgemm) -> Z streams only Wb_h (128 KB).
// Streamed/step (XC=1, pin holds): 128 + 15*16 = 368 KB -> ~2.9 us/step.
template <int XC, int INLINE_Y>
__global__ __launch_bounds__(NT1, 4) void cfc3(
    const float* __restrict__ x, const float* __restrict__ ts,
    const float* __restrict__ bb, const float* __restrict__ bf1,
    const float* __restrict__ bf2, const float* __restrict__ bta,
    const float* __restrict__ btb, const float* __restrict__ bo,
    _Float16* __restrict__ ws, float* __restrict__ out) {
  __shared__ __align__(16) _Float16 xh[KBB];   // [0,128): x_t  [128,384): h
  __shared__ __align__(16) _Float16 zf[Hn];
  __shared__ float tsb[Sn];
  __shared__ float scrZ[768];
  __shared__ float scrH[768];
  __shared__ float scrY[896];
  extern __shared__ _Float16 sWH[];            // [NL][1024][8] halves

  const int tid = threadIdx.x;
  const int b = blockIdx.x;
  const _Float16* Wb_p = ws + WB_OFF;
  const _Float16* W4_p = ws + W4_OFF;
  const _Float16* Wo_p = ws + WO_OFF;
  _Float16* hbuf = ws + HBUF_OFF;
  const _Float16* xcp = ws + XC_OFF;

  const float* xrow  = x  + (size_t)b * Sn * FIN;
  const float* tsrow = ts + (size_t)b * Sn;
  float*       orow  = out + (size_t)b * Sn * FOUT;

  // ---- per-role constants ----
  const int jq = tid & 255;          // column within a 256 group
  const int kw = tid >> 8;           // Z K-split group (0..3), wave-uniform
  const float bbj = (tid < 256) ? bb[tid] : 0.f;
  const float bH = (kw == 0 ? bf1 : kw == 1 ? bf2 : kw == 2 ? bta : btb)[jq];
  const int jY = tid & 127, kq = tid >> 7;
  const float boj = (tid < 128) ? bo[tid] : 0.f;

  // Z weight base: XC=1 streams only the h-part (layers 16-47, K=256 split 4
  // ways -> 8 chunks); XC=0 streams full Wb (layers 0-47 -> 12 chunks).
  const _Float16* gZ = XC
      ? Wb_p + (size_t)(16 + kw * 8) * 2048 + (size_t)jq * 8
      : Wb_p + (size_t)(kw * 12) * 2048 + (size_t)jq * 8;
  const _Float16* gH = W4_p + (size_t)tid * 8;                     // 32 chunks
  const _Float16* gY = Wo_p + ((size_t)(kq * 4) * 128 + jY) * 8;   // 4 chunks

  // ---- one-time weight residency ----
  h8 wH[NV];                                  // chunks [0,NV) in VGPRs
#pragma unroll
  for (int c = 0; c < NV; ++c) wH[c] = *(const h8*)(gH + (size_t)c * 8192);
#pragma unroll
  for (int c = 0; c < NV; ++c) asm volatile("" : "+v"(wH[c]));   // pin
#pragma unroll
  for (int cc = 0; cc < NL; ++cc)             // chunks [NV,NV+NL) in LDS
    *(h8*)(sWH + (size_t)cc * 8192 + tid * 8) =
        *(const h8*)(gH + (size_t)(NV + cc) * 8192);

  // ---- one-time staging ----
  tsb[tid] = tsrow[tid];                       // NT1 == Sn
  if (tid < 128) ((unsigned*)xh)[64 + tid] = 0;   // h0 = 0 (halves [128,384))
  if (XC == 0 && tid < 64) {                   // x(0) (XC=0 only)
    float2 xv = *(const float2*)(xrow + 2 * tid);
    h2 p; p[0] = (_Float16)xv.x; p[1] = (_Float16)xv.y;
    *(h2*)&xh[2 * tid] = p;
  }
  __syncthreads();

  for (int st = 0; st < Sn; ++st) {
    // xc(t) prefetch (XC=1): issued at loop top, consumed after B1.
    float xcv = 0.f;
    if (XC && tid < 256)
      xcv = (float)xcp[((size_t)b * Sn + st) * 256 + tid];

    // x(t+1) prefetch (XC=0, wave 15)
    float2 xv; xv.x = 0.f; xv.y = 0.f;
    if (XC == 0 && tid >= 960 && st + 1 < Sn)
      xv = *(const float2*)(xrow + (size_t)(st + 1) * FIN + 2 * (tid - 960));

    // ---- Z: z = tanh([x,h] @ Wb + bb), K split 4 wave-groups ----
    float a0 = 0.f, a1 = 0.f, a2 = 0.f, a3 = 0.f;
    if (XC) {
#pragma unroll 4
      for (int c = 0; c < 8; ++c) {                     // h-part only, K=256
        h8 v = *(const h8*)&xh[128 + (kw * 8 + c) * 8]; // LDS broadcast
        h8 w = *(const h8*)(gZ + (size_t)c * 2048);
        dot8_4(v, w, a0, a1, a2, a3);
      }
    } else {
#pragma unroll 4
      for (int c = 0; c < 12; ++c) {                    // full K=384
        h8 v = *(const h8*)&xh[(kw * 12 + c) * 8];
        h8 w = *(const h8*)(gZ + (size_t)c * 2048);
        dot8_4(v, w, a0, a1, a2, a3);
      }
    }
    float zs = a0 + a1 + a2 + a3;
    if (tid >= 256) scrZ[tid - 256] = zs;
    __syncthreads();                     // B1: Z xh-reads done, scrZ ready
    if (tid < 256) {
      float zp = zs + scrZ[tid] + scrZ[256 + tid] + scrZ[512 + tid] + bbj;
      if (XC) zp += xcv;
      zf[tid] = (_Float16)tanhf(zp);
    }
    if (XC == 0 && tid >= 960 && st + 1 < Sn) {  // commit x(t+1); safe after B1
      h2 p; p[0] = (_Float16)xv.x; p[1] = (_Float16)xv.y;
      *(h2*)&xh[2 * (tid - 960)] = p;
    }
    __syncthreads();                     // B2: zf ready

    // ---- H: col n = tid of [ff1|ff2|ta|tb], K=256 ----
    // streamed chunks first (loads in flight), unroll 2 to cap reg pressure
    float s0 = 0.f, s1 = 0.f, s2 = 0.f, s3 = 0.f;
#pragma unroll 2
    for (int c = NV + NL; c < 32; ++c) {
      h8 v = *(const h8*)&zf[c * 8];
      h8 w = *(const h8*)(gH + (size_t)c * 8192);       // 1 KB/wave contiguous
      dot8_4(v, w, s0, s1, s2, s3);
    }
    float b0 = 0.f, b1 = 0.f, b2 = 0.f, b3 = 0.f;
    // VGPR-resident chunks (pinned)
#pragma unroll
    for (int c = 0; c < NV; ++c) {
      h8 v = *(const h8*)&zf[c * 8];                    // LDS broadcast
      dot8_4(v, wH[c], b0, b1, b2, b3);
    }
    // LDS-resident chunks
#pragma unroll
    for (int cc = 0; cc < NL; ++cc) {
      h8 v = *(const h8*)&zf[(NV + cc) * 8];
      h8 w = *(const h8*)(sWH + (size_t)cc * 8192 + tid * 8);
      dot8_4(v, w, b0, b1, b2, b3);
    }
    float g = (b0 + s0) + (b1 + s1) + (b2 + s2) + (b3 + s3) + bH;
    if (tid >= 256) scrH[tid - 256] = g;
    __syncthreads();                     // B3: scrH ready
    if (tid < 256) {
      float ff2 = scrH[tid], ta = scrH[256 + tid], tb = scrH[512 + tid];
      float tt = tsb[st];
      float sg = 1.f / (1.f + __expf(-(ta * tt + tb)));
      float hn = tanhf(g) * (1.f - sg) + sg * tanhf(ff2);
      xh[128 + tid] = (_Float16)hn;
      if (!INLINE_Y)
        hbuf[((size_t)b * Sn + st) * Hn + tid] = (_Float16)hn;
    }
    __syncthreads();                     // B4: h ready

    if (INLINE_Y) {
      // ---- Y: y = h @ Wout + bo, K split 8 ways ----
      float y0 = 0.f, y1 = 0.f, y2 = 0.f, y3 = 0.f;
#pragma unroll
      for (int c = 0; c < 4; ++c) {
        h8 v = *(const h8*)&xh[128 + (kq * 4 + c) * 8];
        h8 w = *(const h8*)(gY + (size_t)c * 1024);
        dot8_4(v, w, y0, y1, y2, y3);
      }
      float ys = y0 + y1 + y2 + y3;
      if (tid >= 128) scrY[tid - 128] = ys;
      __syncthreads();                   // B5
      if (tid < 128) {
        float y = ys + boj;
#pragma unroll
        for (int p = 0; p < 7; ++p) y += scrY[128 * p + tid];
        orow[(size_t)st * FOUT + tid] = y;
      }
    }
  }
}

// Phase 2 (split path): y[BS,128] = h[BS,256] @ Wout + bo. Wout LDS-resident,
// h rows staged 8 at a time; 512 WGs x 256 threads over all 256 CUs.
#define SMEMY (65536 + 4096)
extern "C" __global__ __launch_bounds__(256, 4)
void ygemm(const _Float16* __restrict__ ws, const float* __restrict__ bo,
           float* __restrict__ out) {
  extern __shared__ char ysm[];
  _Float16* sWo = (_Float16*)ysm;            // 32768 halves
  _Float16* sH  = (_Float16*)(ysm + 65536);  // 8 x 256 halves
  const int tid = threadIdx.x;
  { const uint4* g = (const uint4*)(ws + WO_OFF);
    uint4* l = (uint4*)sWo;
#pragma unroll
    for (int i = 0; i < 16; ++i) l[tid + 256 * i] = g[tid + 256 * i]; }
  const _Float16* hb = ws + HBUF_OFF;
  const int row0 = blockIdx.x * 256;
  const int j = tid & 127, rh = tid >> 7;
  const float boj = bo[j];
  for (int it = 0; it < 32; ++it) {
    const int rbase = row0 + it * 8;
    __syncthreads();                         // sH reads from prev iter done
    ((uint4*)sH)[tid] = ((const uint4*)(hb + (size_t)rbase * 256))[tid];
    __syncthreads();
#pragma unroll
    for (int rr = rh; rr < 8; rr += 2) {
      float y0 = 0.f, y1 = 0.f, y2 = 0.f, y3 = 0.f;
#pragma unroll 4
      for (int c = 0; c < 32; ++c) {
        h8 v = *(const h8*)&sH[rr * 256 + c * 8];       // broadcast
        h8 w = *(const h8*)&sWo[((size_t)c * 128 + j) * 8];
        dot8_4(v, w, y0, y1, y2, y3);
      }
      out[(size_t)(rbase + rr) * 128 + j] = y0 + y1 + y2 + y3 + boj;
    }
  }
}

extern "C" void kernel_launch(void* const* d_in, const int* in_sizes, int n_in,
                              void* d_out, int out_size, void* d_ws, size_t ws_size,
                              hipStream_t stream) {
  const float* x   = (const float*)d_in[0];
  const float* ts  = (const float*)d_in[1];
  const float* Wb  = (const float*)d_in[2];
  const float* bb  = (const float*)d_in[3];
  const float* W1  = (const float*)d_in[4];
  const float* bf1 = (const float*)d_in[5];
  const float* W2  = (const float*)d_in[6];
  const float* bf2 = (const float*)d_in[7];
  const float* W3  = (const float*)d_in[8];
  const float* bta = (const float*)d_in[9];
  const float* W4  = (const float*)d_in[10];
  const float* btb = (const float*)d_in[11];
  const float* Wo  = (const float*)d_in[12];
  const float* bo  = (const float*)d_in[13];
  float* out = (float*)d_out;
  _Float16* ws = (_Float16*)d_ws;

  pack_w<<<WS_HALVES / 256, 256, 0, stream>>>(Wb, W1, W2, W3, W4, Wo, ws);

  if (ws_size >= WS_FULL_BYTES) {
    xgemm<<<(Bn * Sn) / 64, 256, 0, stream>>>(x, ws, ws + XC_OFF);
    hipFuncSetAttribute((const void*)(cfc3<1, 0>),
                        hipFuncAttributeMaxDynamicSharedMemorySize, DYN_SMEM);
    cfc3<1, 0><<<Bn, NT1, DYN_SMEM, stream>>>(x, ts, bb, bf1, bf2, bta, btb, bo, ws, out);
    hipFuncSetAttribute((const void*)ygemm,
                        hipFuncAttributeMaxDynamicSharedMemorySize, SMEMY);
    ygemm<<<(Bn * Sn) / 256, 256, SMEMY, stream>>>(ws, bo, out);
  } else if (ws_size >= WS_SPLIT_BYTES) {
    hipFuncSetAttribute((const void*)(cfc3<0, 0>),
                        hipFuncAttributeMaxDynamicSharedMemorySize, DYN_SMEM);
    cfc3<0, 0><<<Bn, NT1, DYN_SMEM, stream>>>(x, ts, bb, bf1, bf2, bta, btb, bo, ws, out);
    hipFuncSetAttribute((const void*)ygemm,
                        hipFuncAttributeMaxDynamicSharedMemorySize, SMEMY);
    ygemm<<<(Bn * Sn) / 256, 256, SMEMY, stream>>>(ws, bo, out);
  } else {
    hipFuncSetAttribute((const void*)(cfc3<0, 1>),
                        hipFuncAttributeMaxDynamicSharedMemorySize, DYN_SMEM);
    cfc3<0, 1><<<Bn, NT1, DYN_SMEM, stream>>>(x, ts, bb, bf1, bf2, bta, btb, bo, ws, out);
  }
}

// Round 5
// 4162.413 us; speedup vs baseline: 1.1945x; 1.1945x over previous
//
#include <hip/hip_runtime.h>

// B=128, S=1024, F_IN=128, H=256, BB=256, F_OUT=128
#define Bn   128
#define Sn   1024
#define FIN  128
#define Hn   256
#define FOUT 128
#define KBB  384
#define NT1  512    // phase-1 threads (8 waves, 2/SIMD -> 256-VGPR budget)

// W4 K-chunk partition per column (32 chunks of 16B):
//   [0,NR4)        reg-resident, asm-pinned (2 cols/thread -> 2*NR4*4 VGPRs)
//   [NR4,NR4+NL4)  LDS-resident
//   rest           streamed from L2 each step
// Rounds 2-4 lesson: at NT=1024 the 128-reg cap makes the allocator spill ALL
// pinned weights (VGPR_Count 64/60/48 observed). NT=512 + bounds(512,2) gives
// a 256-reg budget; demand ~220 leaves real headroom.
#define NR4 20
#define NL4 1
#define DYN_SMEM ((32 * 256 * 8 + NL4 * 1024 * 8) * 2)   // Wb_h 128KB + W4L 16KB

// packed weight layout in d_ws (halves):
//   Wb_p [48][256][8]  -> 98304   (chunks 0-15 = x-part, 16-47 = h-part)
//   W4_p [32][1024][8] -> 262144  (N = [ff1|ff2|ta|tb])
//   Wo_p [32][128][8]  -> 32768
//   hbuf [B*S*H]  fp16 (split-Y path)
//   xc   [B*S*BB] fp16 (precomputed x @ Wb_x)
#define WB_OFF 0
#define W4_OFF 98304
#define WO_OFF 360448
#define WS_HALVES 393216
#define HBUF_OFF WS_HALVES
#define XC_OFF (HBUF_OFF + (size_t)Bn * Sn * Hn)
#define WS_SPLIT_BYTES ((size_t)(WS_HALVES + (size_t)Bn * Sn * Hn) * 2)
#define WS_FULL_BYTES ((XC_OFF + (size_t)Bn * Sn * Hn) * 2)

typedef _Float16 h2 __attribute__((ext_vector_type(2)));
typedef _Float16 h8 __attribute__((ext_vector_type(8)));

__device__ __forceinline__ float dot2f(h2 a, h2 b, float c) {
#if __has_builtin(__builtin_amdgcn_fdot2)
  return __builtin_amdgcn_fdot2(a, b, c, false);   // v_dot2_f32_f16
#else
  return c + (float)a[0] * (float)b[0] + (float)a[1] * (float)b[1];
#endif
}
__device__ __forceinline__ void dot8_4(h8 v, h8 w, float& c0, float& c1, float& c2, float& c3) {
  h2 v0 = {v[0], v[1]}, v1 = {v[2], v[3]}, v2 = {v[4], v[5]}, v3 = {v[6], v[7]};
  h2 w0 = {w[0], w[1]}, w1 = {w[2], w[3]}, w2 = {w[4], w[5]}, w3 = {w[6], w[7]};
  c0 = dot2f(v0, w0, c0); c1 = dot2f(v1, w1, c1);
  c2 = dot2f(v2, w2, c2); c3 = dot2f(v3, w3, c3);
}

// fp32 -> fp16 packing (verified layout)
__global__ __launch_bounds__(256) void pack_w(
    const float* __restrict__ Wb, const float* __restrict__ W1,
    const float* __restrict__ W2, const float* __restrict__ W3,
    const float* __restrict__ W4, const float* __restrict__ Wo,
    _Float16* __restrict__ ws) {
  int p = blockIdx.x * 256 + threadIdx.x;
  if (p >= WS_HALVES) return;
  float v;
  if (p < W4_OFF) {                       // backbone [384,256] row-major
    int r = p & 7, j = (p >> 3) & 255;
    int k = ((p >> 11) << 3) | r;
    v = Wb[k * 256 + j];
  } else if (p < WO_OFF) {                // heads concat: N = [ff1|ff2|ta|tb]
    int q = p - W4_OFF;
    int r = q & 7, j = (q >> 3) & 1023;
    int k = ((q >> 13) << 3) | r;
    int jj = j & 255;
    const float* Ws = (j < 256) ? W1 : (j < 512) ? W2 : (j < 768) ? W3 : W4;
    v = Ws[k * 256 + jj];
  } else {                                // Wout [256,128]
    int q = p - WO_OFF;
    int r = q & 7, j = (q >> 3) & 127;
    int k = ((q >> 10) << 3) | r;
    v = Wo[k * 128 + j];
  }
  ws[p] = (_Float16)v;
}

// xc[r,j] = sum_k x[r,k] * Wb[k,j]  (k<128, non-recurrent x-part of Z)
__global__ __launch_bounds__(256) void xgemm(
    const float* __restrict__ x, const _Float16* __restrict__ ws,
    _Float16* __restrict__ xc) {
  __shared__ __align__(16) _Float16 sX[64 * 128];   // 16 KB
  const int tid = threadIdx.x;
  const size_t r0 = (size_t)blockIdx.x * 64;
  const float* xb = x + r0 * 128;
#pragma unroll
  for (int m = 0; m < 32; ++m)
    sX[m * 256 + tid] = (_Float16)xb[m * 256 + tid];
  const _Float16* gX = ws + WB_OFF + (size_t)tid * 8;   // chunks 0-15 = x-part
  h8 wx[16];
#pragma unroll
  for (int L = 0; L < 16; ++L) wx[L] = *(const h8*)(gX + (size_t)L * 2048);
  __syncthreads();
  for (int r = 0; r < 64; ++r) {
    float c0 = 0.f, c1 = 0.f, c2 = 0.f, c3 = 0.f;
#pragma unroll
    for (int L = 0; L < 16; ++L) {
      h8 v = *(const h8*)&sX[r * 128 + L * 8];          // broadcast
      dot8_4(v, wx[L], c0, c1, c2, c3);
    }
    xc[(r0 + r) * 256 + tid] = (_Float16)(c0 + c1 + c2 + c3);
  }
}

// Phase 1: one 512-thread WG per batch element.
// Thread roles:
//   Z: col jz = tid&255, K-half kz = tid>>8 (Wb_h LDS-resident, xc precomputed)
//   H: colA = tid (ff1|ff2), colB = tid+512 (ta|tb); full K per thread.
//   combine: thread n<256 holds ff1[n],ta[n]; thread n+256 ships ff2[n],tb[n]
//            via scrH.
// Streamed weights/step: (32-NR4-NL4) chunks x 2 cols x 16 B x 512 thr = 176 KB
// -> ~1.3 us at the measured ~55 B/cy per-CU L2 port, + Z LDS 128 KB ~0.6 us.
template <int XC, int INLINE_Y>
__global__ __launch_bounds__(NT1, 2) void cfc5(
    const float* __restrict__ x, const float* __restrict__ ts,
    const float* __restrict__ bb, const float* __restrict__ bf1,
    const float* __restrict__ bf2, const float* __restrict__ bta,
    const float* __restrict__ btb, const float* __restrict__ bo,
    _Float16* __restrict__ ws, float* __restrict__ out) {
  __shared__ __align__(16) _Float16 xh[KBB];   // [0,128): x_t (XC=0)  [128,384): h
  __shared__ __align__(16) _Float16 zf[Hn];
  __shared__ float tsb[Sn];
  __shared__ float scrZ[256];
  __shared__ float scrH[512];
  extern __shared__ __align__(16) _Float16 dyn[];
  _Float16* sWb  = dyn;                        // [32][256][8] = 128 KB (XC=1)
  _Float16* sW4L = dyn + 32 * 256 * 8;         // [NL4][1024][8] = 16 KB

  const int tid = threadIdx.x;
  const int b = blockIdx.x;
  const _Float16* Wb_p = ws + WB_OFF;
  const _Float16* W4_p = ws + W4_OFF;
  const _Float16* Wo_p = ws + WO_OFF;
  _Float16* hbuf = ws + HBUF_OFF;
  const _Float16* xcp = ws + XC_OFF;

  const float* xrow  = x  + (size_t)b * Sn * FIN;
  const float* tsrow = ts + (size_t)b * Sn;
  float*       orow  = out + (size_t)b * Sn * FOUT;

  // ---- per-role constants ----
  const int jz = tid & 255, kz = tid >> 8;
  const float bbj = (tid < 256) ? bb[tid] : 0.f;
  const float bHA = (tid < 256) ? bf1[tid] : bf2[tid - 256];
  const float bHB = (tid < 256) ? bta[tid] : btb[tid - 256];
  const int jY = tid & 127, kqY = tid >> 7;
  const float boj = bo[jY];

  // ---- one-time LDS staging ----
  if (XC) {                                    // Wb_h (chunks 16-47) -> LDS
    const h8* src = (const h8*)(Wb_p + (size_t)16 * 2048);
    h8* dst = (h8*)sWb;
    for (int i = tid; i < 8192; i += NT1) dst[i] = src[i];
  }
  {                                            // W4 chunks [NR4,NR4+NL4) -> LDS
    const h8* src = (const h8*)(W4_p + (size_t)NR4 * 8192);
    h8* dst = (h8*)sW4L;
    for (int i = tid; i < NL4 * 1024; i += NT1) dst[i] = src[i];
  }
  for (int i = tid; i < Sn; i += NT1) tsb[i] = tsrow[i];
  if (tid < 128) ((unsigned*)xh)[64 + tid] = 0;   // h0 = 0
  if (!XC && tid < 64) {                       // x(0) (XC=0 only)
    float2 xv = *(const float2*)(xrow + 2 * tid);
    h2 p; p[0] = (_Float16)xv.x; p[1] = (_Float16)xv.y;
    *(h2*)&xh[2 * tid] = p;
  }

  // ---- one-time W4 register residency (2 cols x NR4 chunks, pinned) ----
  const _Float16* gA = W4_p + (size_t)tid * 8;         // colA = tid
  const _Float16* gB = W4_p + (size_t)(tid + 512) * 8; // colB = tid+512
  h8 wA[NR4], wBv[NR4];
#pragma unroll
  for (int c = 0; c < NR4; ++c) {
    wA[c]  = *(const h8*)(gA + (size_t)c * 8192);
    wBv[c] = *(const h8*)(gB + (size_t)c * 8192);
  }
#pragma unroll
  for (int c = 0; c < NR4; ++c) {
    asm volatile("" : "+v"(wA[c]));
    asm volatile("" : "+v"(wBv[c]));
  }
  __syncthreads();

  for (int st = 0; st < Sn; ++st) {
    // xc(t) prefetch (XC=1; consumed after B1)
    float xcv = 0.f;
    if (XC && tid < 256)
      xcv = (float)xcp[((size_t)b * Sn + st) * 256 + tid];
    // x(t+1) prefetch (XC=0; threads 448..511)
    float2 xv; xv.x = 0.f; xv.y = 0.f;
    if (!XC && tid >= 448 && st + 1 < Sn)
      xv = *(const float2*)(xrow + (size_t)(st + 1) * FIN + 2 * (tid - 448));

    // ---- Z: z = tanh(xc + h @ Wb_h + bb), K split 2 ----
    float a0 = 0.f, a1 = 0.f, a2 = 0.f, a3 = 0.f;
    if (XC) {
#pragma unroll 4
      for (int c = 0; c < 16; ++c) {
        int kc = kz * 16 + c;
        h8 v = *(const h8*)&xh[128 + kc * 8];
        h8 w = *(const h8*)&sWb[((size_t)kc * 256 + jz) * 8];   // LDS
        dot8_4(v, w, a0, a1, a2, a3);
      }
    } else {
      const _Float16* gZ = Wb_p + ((size_t)(kz * 24) * 256 + jz) * 8;
#pragma unroll 4
      for (int c = 0; c < 24; ++c) {
        h8 v = *(const h8*)&xh[(kz * 24 + c) * 8];
        h8 w = *(const h8*)(gZ + (size_t)c * 2048);
        dot8_4(v, w, a0, a1, a2, a3);
      }
    }
    float zs = a0 + a1 + a2 + a3;
    if (kz) scrZ[jz] = zs;
    __syncthreads();                     // B1: Z reads done, scrZ ready
    if (tid < 256) {
      float zp = zs + scrZ[tid] + bbj;
      if (XC) zp += xcv;
      zf[tid] = (_Float16)tanhf(zp);
    }
    if (!XC && tid >= 448 && st + 1 < Sn) {   // commit x(t+1); safe after B1
      h2 p; p[0] = (_Float16)xv.x; p[1] = (_Float16)xv.y;
      *(h2*)&xh[2 * (tid - 448)] = p;
    }
    __syncthreads();                     // B2: zf ready

    // ---- H: 2 cols/thread, K=256 ----
    float hA0 = 0.f, hA1 = 0.f, hA2 = 0.f, hA3 = 0.f;
    float hB0 = 0.f, hB1 = 0.f, hB2 = 0.f, hB3 = 0.f;
    // streamed chunks first (loads in flight under the resident compute)
#pragma unroll 2
    for (int c = NR4 + NL4; c < 32; ++c) {
      h8 v  = *(const h8*)&zf[c * 8];
      h8 wa = *(const h8*)(gA + (size_t)c * 8192);
      h8 wb = *(const h8*)(gB + (size_t)c * 8192);
      dot8_4(v, wa, hA0, hA1, hA2, hA3);
      dot8_4(v, wb, hB0, hB1, hB2, hB3);
    }
    // reg-resident chunks
#pragma unroll
    for (int c = 0; c < NR4; ++c) {
      h8 v = *(const h8*)&zf[c * 8];
      dot8_4(v, wA[c],  hA0, hA1, hA2, hA3);
      dot8_4(v, wBv[c], hB0, hB1, hB2, hB3);
    }
    // LDS-resident chunks
#pragma unroll
    for (int l = 0; l < NL4; ++l) {
      h8 v  = *(const h8*)&zf[(NR4 + l) * 8];
      h8 wa = *(const h8*)&sW4L[((size_t)l * 1024 + tid) * 8];
      h8 wb = *(const h8*)&sW4L[((size_t)l * 1024 + tid + 512) * 8];
      dot8_4(v, wa, hA0, hA1, hA2, hA3);
      dot8_4(v, wb, hB0, hB1, hB2, hB3);
    }
    float gAv = hA0 + hA1 + hA2 + hA3 + bHA;   // ff1 (tid<256) / ff2
    float gBv = hB0 + hB1 + hB2 + hB3 + bHB;   // ta  (tid<256) / tb
    if (tid >= 256) {
      scrH[tid - 256]       = gAv;             // ff2[n]
      scrH[256 + tid - 256] = gBv;             // tb[n]
    }
    __syncthreads();                     // B3
    if (tid < 256) {
      float ff2v = scrH[tid], tbv = scrH[256 + tid];
      float tt = tsb[st];
      float sg = 1.f / (1.f + __expf(-(gBv * tt + tbv)));
      float hn = tanhf(gAv) * (1.f - sg) + sg * tanhf(ff2v);
      xh[128 + tid] = (_Float16)hn;
      if (!INLINE_Y)
        hbuf[((size_t)b * Sn + st) * Hn + tid] = (_Float16)hn;
    }
    __syncthreads();                     // B4: h ready

    if (INLINE_Y) {
      // ---- Y: y = h @ Wout + bo, K split 4 (scrH reused post-B4) ----
      const _Float16* gY = Wo_p + ((size_t)(kqY * 8) * 128 + jY) * 8;
      float y0 = 0.f, y1 = 0.f, y2 = 0.f, y3 = 0.f;
#pragma unroll
      for (int c = 0; c < 8; ++c) {
        h8 v = *(const h8*)&xh[128 + (kqY * 8 + c) * 8];
        h8 w = *(const h8*)(gY + (size_t)c * 1024);
        dot8_4(v, w, y0, y1, y2, y3);
      }
      float ysv = y0 + y1 + y2 + y3;
      if (kqY) scrH[(kqY - 1) * 128 + jY] = ysv;
      __syncthreads();                   // B5
      if (kqY == 0) {
        float y = ysv + boj + scrH[jY] + scrH[128 + jY] + scrH[256 + jY];
        orow[(size_t)st * FOUT + jY] = y;
      }
    }
  }
}

// Phase 2 (split path): y[BS,128] = h[BS,256] @ Wout + bo
#define SMEMY (65536 + 4096)
extern "C" __global__ __launch_bounds__(256, 4)
void ygemm(const _Float16* __restrict__ ws, const float* __restrict__ bo,
           float* __restrict__ out) {
  extern __shared__ char ysm[];
  _Float16* sWo = (_Float16*)ysm;            // 32768 halves
  _Float16* sH  = (_Float16*)(ysm + 65536);  // 8 x 256 halves
  const int tid = threadIdx.x;
  { const uint4* g = (const uint4*)(ws + WO_OFF);
    uint4* l = (uint4*)sWo;
#pragma unroll
    for (int i = 0; i < 16; ++i) l[tid + 256 * i] = g[tid + 256 * i]; }
  const _Float16* hb = ws + HBUF_OFF;
  const int row0 = blockIdx.x * 256;
  const int j = tid & 127, rh = tid >> 7;
  const float boj = bo[j];
  for (int it = 0; it < 32; ++it) {
    const int rbase = row0 + it * 8;
    __syncthreads();                         // sH reads from prev iter done
    ((uint4*)sH)[tid] = ((const uint4*)(hb + (size_t)rbase * 256))[tid];
    __syncthreads();
#pragma unroll
    for (int rr = rh; rr < 8; rr += 2) {
      float y0 = 0.f, y1 = 0.f, y2 = 0.f, y3 = 0.f;
#pragma unroll 4
      for (int c = 0; c < 32; ++c) {
        h8 v = *(const h8*)&sH[rr * 256 + c * 8];       // broadcast
        h8 w = *(const h8*)&sWo[((size_t)c * 128 + j) * 8];
        dot8_4(v, w, y0, y1, y2, y3);
      }
      out[(size_t)(rbase + rr) * 128 + j] = y0 + y1 + y2 + y3 + boj;
    }
  }
}

extern "C" void kernel_launch(void* const* d_in, const int* in_sizes, int n_in,
                              void* d_out, int out_size, void* d_ws, size_t ws_size,
                              hipStream_t stream) {
  const float* x   = (const float*)d_in[0];
  const float* ts  = (const float*)d_in[1];
  const float* Wb  = (const float*)d_in[2];
  const float* bb  = (const float*)d_in[3];
  const float* W1  = (const float*)d_in[4];
  const float* bf1 = (const float*)d_in[5];
  const float* W2  = (const float*)d_in[6];
  const float* bf2 = (const float*)d_in[7];
  const float* W3  = (const float*)d_in[8];
  const float* bta = (const float*)d_in[9];
  const float* W4  = (const float*)d_in[10];
  const float* btb = (const float*)d_in[11];
  const float* Wo  = (const float*)d_in[12];
  const float* bo  = (const float*)d_in[13];
  float* out = (float*)d_out;
  _Float16* ws = (_Float16*)d_ws;

  pack_w<<<WS_HALVES / 256, 256, 0, stream>>>(Wb, W1, W2, W3, W4, Wo, ws);

  if (ws_size >= WS_FULL_BYTES) {
    xgemm<<<(Bn * Sn) / 64, 256, 0, stream>>>(x, ws, ws + XC_OFF);
    hipFuncSetAttribute((const void*)(cfc5<1, 0>),
                        hipFuncAttributeMaxDynamicSharedMemorySize, DYN_SMEM);
    cfc5<1, 0><<<Bn, NT1, DYN_SMEM, stream>>>(x, ts, bb, bf1, bf2, bta, btb, bo, ws, out);
    hipFuncSetAttribute((const void*)ygemm,
                        hipFuncAttributeMaxDynamicSharedMemorySize, SMEMY);
    ygemm<<<(Bn * Sn) / 256, 256, SMEMY, stream>>>(ws, bo, out);
  } else if (ws_size >= WS_SPLIT_BYTES) {
    hipFuncSetAttribute((const void*)(cfc5<0, 0>),
                        hipFuncAttributeMaxDynamicSharedMemorySize, DYN_SMEM);
    cfc5<0, 0><<<Bn, NT1, DYN_SMEM, stream>>>(x, ts, bb, bf1, bf2, bta, btb, bo, ws, out);
    hipFuncSetAttribute((const void*)ygemm,
                        hipFuncAttributeMaxDynamicSharedMemorySize, SMEMY);
    ygemm<<<(Bn * Sn) / 256, 256, SMEMY, stream>>>(ws, bo, out);
  } else {
    hipFuncSetAttribute((const void*)(cfc5<0, 1>),
                        hipFuncAttributeMaxDynamicSharedMemorySize, DYN_SMEM);
    cfc5<0, 1><<<Bn, NT1, DYN_SMEM, stream>>>(x, ts, bb, bf1, bf2, bta, btb, bo, ws, out);
  }
}